// Round 5
// baseline (167.733 us; speedup 1.0000x reference)
//
#include <hip/hip_runtime.h>
#include <math.h>

// HumanPoseModule: (BT,10,6) + (BT,6,6) f32 -> (BT,24,3) f32 axis-angle.
//
// R11: R7's root-free algebra + TRUE ILP2 + NON-TEMPORAL STORES.
// Evidence trail: R7 scattered loads (47.5us) == R10 LDS-staged coalesced
// loads (49us) -> input path exonerated. No pipe saturated (VALU<50%,
// HBM 32%, LDS ~0) -> latency-bound with ~26us exposed; each wave carries
// ONE element-chain so ~5 chains/SIMD is all the hiding available.
// R8's ILP2 was serialized by regalloc (VGPR stuck at 32 under the default
// occupancy heuristic). R11 fixes that two ways:
//   (1) statement-level A/B interleave of the whole pipeline (rot6d2 /
//       matTmul2 / mat2aa2) so the schedule is interleaved by construction;
//   (2) __launch_bounds__(256, 4) -> VGPR cap 128, removing the pressure
//       heuristic that forced serialization. MARKER: VGPR_Count >= ~70
//       means the interleave materialized.
// NT stores: bench re-dispatches on the same buffers; output (75MB) was
// evicting the 96MB of inputs from the 256MB L3 between dispatches
// (FETCH 49MB/dispatch). __builtin_nontemporal_store on all outputs keeps
// inputs L3-resident. MARKER: FETCH_SIZE well below 49MB.
//
// Identity (R7): full[j] = root @ X_j, root orthonormal =>
// local[j] = X_parent^T @ X_j; joints 1,2,3: local = X_j; joint 0: root.
//
// Lane tables (byte-packed u64s; lane l = tid&15):
//   joints: {0,1,2,3,4,5,6,9,12,13,14,15,16,17,18,19}
//   srcj:   sel<<4|row  (sel 0 = glb row, 1 = ori row)
//   pl:     parent's lane within the 16-group (lanes 0-3 unused: direct)
// Ignored joints {7,8,10,11,20,21,22,23} -> zeros, written by lanes 0-7.

__device__ __forceinline__ void rot6d2(float2 p0, float2 p1, float2 p2,
                                       float2 q0, float2 q1, float2 q2,
                                       float A[3][3], float B[3][3]) {
    float a1xA = p0.x, a1yA = p0.y, a1zA = p1.x;
    float a2xA = p1.y, a2yA = p2.x, a2zA = p2.y;
    float a1xB = q0.x, a1yB = q0.y, a1zB = q1.x;
    float a2xB = q1.y, a2yB = q2.x, a2zB = q2.y;
    float r1A = __builtin_amdgcn_rsqf(a1xA * a1xA + a1yA * a1yA + a1zA * a1zA);
    float r1B = __builtin_amdgcn_rsqf(a1xB * a1xB + a1yB * a1yB + a1zB * a1zB);
    float b1xA = a1xA * r1A, b1yA = a1yA * r1A, b1zA = a1zA * r1A;
    float b1xB = a1xB * r1B, b1yB = a1yB * r1B, b1zB = a1zB * r1B;
    float dtA = b1xA * a2xA + b1yA * a2yA + b1zA * a2zA;
    float dtB = b1xB * a2xB + b1yB * a2yB + b1zB * a2zB;
    float c2xA = a2xA - dtA * b1xA, c2yA = a2yA - dtA * b1yA, c2zA = a2zA - dtA * b1zA;
    float c2xB = a2xB - dtB * b1xB, c2yB = a2yB - dtB * b1yB, c2zB = a2zB - dtB * b1zB;
    float r2A = __builtin_amdgcn_rsqf(c2xA * c2xA + c2yA * c2yA + c2zA * c2zA);
    float r2B = __builtin_amdgcn_rsqf(c2xB * c2xB + c2yB * c2yB + c2zB * c2zB);
    float b2xA = c2xA * r2A, b2yA = c2yA * r2A, b2zA = c2zA * r2A;
    float b2xB = c2xB * r2B, b2yB = c2yB * r2B, b2zB = c2zB * r2B;
    float b3xA = b1yA * b2zA - b1zA * b2yA;
    float b3xB = b1yB * b2zB - b1zB * b2yB;
    float b3yA = b1zA * b2xA - b1xA * b2zA;
    float b3yB = b1zB * b2xB - b1xB * b2zB;
    float b3zA = b1xA * b2yA - b1yA * b2xA;
    float b3zB = b1xB * b2yB - b1yB * b2xB;
    A[0][0] = b1xA; A[0][1] = b1yA; A[0][2] = b1zA;
    A[1][0] = b2xA; A[1][1] = b2yA; A[1][2] = b2zA;
    A[2][0] = b3xA; A[2][1] = b3yA; A[2][2] = b3zA;
    B[0][0] = b1xB; B[0][1] = b1yB; B[0][2] = b1zB;
    B[1][0] = b2xB; B[1][1] = b2yB; B[1][2] = b2zB;
    B[2][0] = b3xB; B[2][1] = b3yB; B[2][2] = b3zB;
}

// Ca = Aa^T @ Ba ; Cb = Ab^T @ Bb, interleaved
__device__ __forceinline__ void matTmul2(const float Aa[3][3], const float Ba[3][3], float Ca[3][3],
                                         const float Ab[3][3], const float Bb[3][3], float Cb[3][3]) {
#pragma unroll
    for (int i = 0; i < 3; ++i)
#pragma unroll
        for (int j = 0; j < 3; ++j) {
            Ca[i][j] = Aa[0][i] * Ba[0][j] + Aa[1][i] * Ba[1][j] + Aa[2][i] * Ba[2][j];
            Cb[i][j] = Ab[0][i] * Bb[0][j] + Ab[1][i] * Bb[1][j] + Ab[2][i] * Bb[2][j];
        }
}

// paired mat2aa (incl. atan2), statement-interleaved; outputs in oa/ob
__device__ __forceinline__ void mat2aa2(const float ma[3][3], const float mb[3][3],
                                        float oa[3], float ob[3]) {
    float a00 = ma[0][0], a01 = ma[0][1], a02 = ma[0][2];
    float a10 = ma[1][0], a11 = ma[1][1], a12 = ma[1][2];
    float a20 = ma[2][0], a21 = ma[2][1], a22 = ma[2][2];
    float b00 = mb[0][0], b01 = mb[0][1], b02 = mb[0][2];
    float b10 = mb[1][0], b11 = mb[1][1], b12 = mb[1][2];
    float b20 = mb[2][0], b21 = mb[2][1], b22 = mb[2][2];
    float ta0 = fmaxf(1.f + a00 + a11 + a22, 0.f);
    float tb0 = fmaxf(1.f + b00 + b11 + b22, 0.f);
    float ta1 = fmaxf(1.f + a00 - a11 - a22, 0.f);
    float tb1 = fmaxf(1.f + b00 - b11 - b22, 0.f);
    float ta2 = fmaxf(1.f - a00 + a11 - a22, 0.f);
    float tb2 = fmaxf(1.f - b00 + b11 - b22, 0.f);
    float ta3 = fmaxf(1.f - a00 - a11 + a22, 0.f);
    float tb3 = fmaxf(1.f - b00 - b11 + b22, 0.f);
    // argmax over t == argmax over sqrt(t) (monotonic, same first-max ties)
    int ia = 0; float bva = ta0;
    int ib = 0; float bvb = tb0;
    if (ta1 > bva) { bva = ta1; ia = 1; }
    if (tb1 > bvb) { bvb = tb1; ib = 1; }
    if (ta2 > bva) { bva = ta2; ia = 2; }
    if (tb2 > bvb) { bvb = tb2; ib = 2; }
    if (ta3 > bva) { bva = ta3; ia = 3; }
    if (tb3 > bvb) { bvb = tb3; ib = 3; }
    float bsa = __builtin_amdgcn_sqrtf(bva);   // >= 1 always (sum of t == 4)
    float bsb = __builtin_amdgcn_sqrtf(bvb);
    float s1a = a21 - a12, s2a = a02 - a20, s3a = a10 - a01;
    float s1b = b21 - b12, s2b = b02 - b20, s3b = b10 - b01;
    float p1a = a10 + a01, p2a = a02 + a20, p3a = a12 + a21;
    float p1b = b10 + b01, p2b = b02 + b20, p3b = b12 + b21;
    float wa = (ia == 0) ? bva : (ia == 1) ? s1a : (ia == 2) ? s2a : s3a;
    float wb = (ib == 0) ? bvb : (ib == 1) ? s1b : (ib == 2) ? s2b : s3b;
    float xa = (ia == 0) ? s1a : (ia == 1) ? bva : (ia == 2) ? p1a : p2a;
    float xb = (ib == 0) ? s1b : (ib == 1) ? bvb : (ib == 2) ? p1b : p2b;
    float ya = (ia == 0) ? s2a : (ia == 1) ? p1a : (ia == 2) ? bva : p3a;
    float yb = (ib == 0) ? s2b : (ib == 1) ? p1b : (ib == 2) ? bvb : p3b;
    float za = (ia == 0) ? s3a : (ia == 1) ? p2a : (ia == 2) ? p3a : bva;
    float zb = (ib == 0) ? s3b : (ib == 1) ? p2b : (ib == 2) ? p3b : bvb;
    float inva = 0.5f * __builtin_amdgcn_rcpf(fmaxf(bsa, 0.1f));
    float invb = 0.5f * __builtin_amdgcn_rcpf(fmaxf(bsb, 0.1f));
    wa *= inva; xa *= inva; ya *= inva; za *= inva;
    wb *= invb; xb *= invb; yb *= invb; zb *= invb;
    // unit quaternion: sin(half) == |v|, cos(half) == w
    float na = __builtin_amdgcn_sqrtf(xa * xa + ya * ya + za * za);
    float nb = __builtin_amdgcn_sqrtf(xb * xb + yb * yb + zb * zb);
    // atan2_pos(n, w), minimax atan poly on [0,1], err ~2e-8, interleaved
    float axa = fabsf(wa), axb = fabsf(wb);
    float mxa = fmaxf(na, axa), mxb = fmaxf(nb, axb);
    float mna = fminf(na, axa), mnb = fminf(nb, axb);
    float qa = mna * __builtin_amdgcn_rcpf(mxa);
    float qb = mnb * __builtin_amdgcn_rcpf(mxb);
    float sa = qa * qa, sb = qb * qb;
    float pa = -0.0040540580f, pb = -0.0040540580f;
    pa = fmaf(pa, sa, 0.0218612288f);  pb = fmaf(pb, sb, 0.0218612288f);
    pa = fmaf(pa, sa, -0.0559098861f); pb = fmaf(pb, sb, -0.0559098861f);
    pa = fmaf(pa, sa, 0.0964200441f);  pb = fmaf(pb, sb, 0.0964200441f);
    pa = fmaf(pa, sa, -0.1390853351f); pb = fmaf(pb, sb, -0.1390853351f);
    pa = fmaf(pa, sa, 0.1994653599f);  pb = fmaf(pb, sb, 0.1994653599f);
    pa = fmaf(pa, sa, -0.3332985605f); pb = fmaf(pb, sb, -0.3332985605f);
    pa = fmaf(pa, sa, 0.9999993329f);  pb = fmaf(pb, sb, 0.9999993329f);
    float ra = pa * qa, rb = pb * qb;
    ra = (na > axa) ? (1.5707963268f - ra) : ra;
    rb = (nb > axb) ? (1.5707963268f - rb) : rb;
    ra = (wa < 0.f) ? (3.1415926536f - ra) : ra;
    rb = (wb < 0.f) ? (3.1415926536f - rb) : rb;
    float anga = 2.f * ra, angb = 2.f * rb;
    // angle < 1e-6 => ref's (0.5 - angle^2/48) rounds to 0.5 => inv_sh = 2
    float isa = (anga < 1e-6f) ? 2.f : anga * __builtin_amdgcn_rcpf(na);
    float isb = (angb < 1e-6f) ? 2.f : angb * __builtin_amdgcn_rcpf(nb);
    oa[0] = xa * isa; oa[1] = ya * isa; oa[2] = za * isa;
    ob[0] = xb * isb; ob[1] = yb * isb; ob[2] = zb * isb;
}

__global__ __launch_bounds__(256, 4) void pose_kernel(const float* __restrict__ glb,
                                                      const float* __restrict__ ori,
                                                      float* __restrict__ out, int BT) {
    int tid = blockIdx.x * 256 + threadIdx.x;
    int pr = tid >> 4;
    int e0 = pr << 1;
    if (e0 >= BT) return;
    int l = tid & 15;
    int e1 = e0 + 1;
    bool live1 = e1 < BT;
    int e1c = live1 ? e1 : e0;   // clamp loads; stores guarded

    // byte-packed per-lane tables
    const unsigned long long OUT3_LO = 0x1B120F0C09060300ULL;  // joint*3, lanes 0-7
    const unsigned long long OUT3_HI = 0x393633302D2A2724ULL;  // lanes 8-15
    const unsigned long long SRCJ_LO = 0x0403121102010010ULL;
    const unsigned long long SRCJ_HI = 0x1514090813070605ULL;
    const unsigned long long PL_LO   = 0x0603020100000000ULL;  // parent lane, lanes 4-7
    const unsigned long long PL_HI   = 0x0D0C0A0908070707ULL;  // lanes 8-15
    const unsigned long long IGN3    = 0x45423F3C211E1815ULL;  // ignored joint*3, lanes 0-7

    int sh = (l & 7) * 8;
    int out3 = (int)(((l < 8 ? OUT3_LO : OUT3_HI) >> sh) & 0xFF);
    int srcj = (int)(((l < 8 ? SRCJ_LO : SRCJ_HI) >> sh) & 0xFF);
    int pl   = (int)(((l < 8 ? PL_LO   : PL_HI)   >> sh) & 0xFF);

    int row6 = (srcj & 15) * 6;
    bool from_ori = (srcj & 0x10) != 0;

    // both elements' loads issued up front (6x dwordx2)
    const float* s0 = from_ori ? (ori + (size_t)e0 * 36 + row6)
                               : (glb + (size_t)e0 * 60 + row6);
    const float* s1 = from_ori ? (ori + (size_t)e1c * 36 + row6)
                               : (glb + (size_t)e1c * 60 + row6);
    const float2* A2 = (const float2*)s0;   // rows are 24B -> 8B aligned
    const float2* B2 = (const float2*)s1;
    float2 ua0 = A2[0], ua1 = A2[1], ua2 = A2[2];
    float2 ub0 = B2[0], ub1 = B2[1], ub2 = B2[2];

    // own X for both elements, interleaved by construction
    float Xa[3][3], Xb[3][3];
    rot6d2(ua0, ua1, ua2, ub0, ub1, ub2, Xa, Xb);

    // parent's X from the parent's lane (wave-synchronous, 16-lane groups);
    // all 18 bpermutes issued back-to-back -> one lgkm wait region
    float Xpa[3][3], Xpb[3][3];
    {
        const float* fa = &Xa[0][0]; float* pa_ = &Xpa[0][0];
        const float* fb = &Xb[0][0]; float* pb_ = &Xpb[0][0];
#pragma unroll
        for (int q = 0; q < 9; ++q) {
            pa_[q] = __shfl(fa[q], pl, 16);
            pb_[q] = __shfl(fb[q], pl, 16);
        }
    }

    // local = Xp^T @ X; lanes 0-3: local = X (parent is root / joint 0 is root)
    float La[3][3], Lb[3][3];
    matTmul2(Xpa, Xa, La, Xpb, Xb, Lb);
#pragma unroll
    for (int i = 0; i < 3; ++i)
#pragma unroll
        for (int j = 0; j < 3; ++j) {
            La[i][j] = (l < 4) ? Xa[i][j] : La[i][j];
            Lb[i][j] = (l < 4) ? Xb[i][j] : Lb[i][j];
        }

    float oa[3], ob[3];
    mat2aa2(La, Lb, oa, ob);

    // non-temporal stores: keep 96MB of inputs L3-resident across dispatches
    float* o0 = out + (size_t)e0 * 72 + out3;
    float* o1 = out + (size_t)e1 * 72 + out3;
    __builtin_nontemporal_store(oa[0], o0 + 0);
    __builtin_nontemporal_store(oa[1], o0 + 1);
    __builtin_nontemporal_store(oa[2], o0 + 2);
    if (live1) {
        __builtin_nontemporal_store(ob[0], o1 + 0);
        __builtin_nontemporal_store(ob[1], o1 + 1);
        __builtin_nontemporal_store(ob[2], o1 + 2);
    }

    // ignored joints -> exact zeros (lanes 0-7, one each, both elements)
    if (l < 8) {
        int z = (int)((IGN3 >> sh) & 0xFF);
        float* zp0 = out + (size_t)e0 * 72 + z;
        __builtin_nontemporal_store(0.f, zp0 + 0);
        __builtin_nontemporal_store(0.f, zp0 + 1);
        __builtin_nontemporal_store(0.f, zp0 + 2);
        if (live1) {
            float* zp1 = out + (size_t)e1 * 72 + z;
            __builtin_nontemporal_store(0.f, zp1 + 0);
            __builtin_nontemporal_store(0.f, zp1 + 1);
            __builtin_nontemporal_store(0.f, zp1 + 2);
        }
    }
}

extern "C" void kernel_launch(void* const* d_in, const int* in_sizes, int n_in,
                              void* d_out, int out_size, void* d_ws, size_t ws_size,
                              hipStream_t stream) {
    const float* glb = (const float*)d_in[0];   // (BT,10,6) f32
    const float* ori = (const float*)d_in[1];   // (BT,6,6)  f32
    float* out = (float*)d_out;                 // (BT,24,3) f32
    int BT = in_sizes[0] / 60;
    long long pairs = ((long long)BT + 1) / 2;
    long long threads = pairs * 16;
    int block = 256;
    int grid = (int)((threads + block - 1) / block);
    pose_kernel<<<grid, block, 0, stream>>>(glb, ori, out, BT);
}

// Round 6
// 151.219 us; speedup vs baseline: 1.1092x; 1.1092x over previous
//
#include <hip/hip_runtime.h>
#include <math.h>

// HumanPoseModule: (BT,10,6) + (BT,6,6) f32 -> (BT,24,3) f32 axis-angle.
//
// R12: R7 base (best: 47.5us/dispatch) + 1024-thread blocks + 32-bit addr math.
// Evidence trail:
//  - R7 scattered loads == R10 LDS-staged loads (47.5 vs 49us) -> input path
//    exonerated; decomposition: VALU issue ~21us + shfl-lgkm ~9us + ~17us
//    common exposure that input staging does NOT touch.
//  - R8/R11: in-thread ILP2 serialized by the compiler every time (VGPR
//    stuck at 32/36) -> abandoned.
//  - R11: nontemporal stores caused 65% write amplification (73.7->122MB,
//    scattered 12B stores bypass L2 write-combining) -> reverted, plain
//    cached stores.
//  - Occupancy never exceeds ~67% with nothing capping it (VGPR 24, LDS 0)
//    -> hypothesis: CP block-dispatch rate limits CU fill for 16K short
//    blocks. R12 tests it: 4096 blocks x 1024 threads (4x fewer dispatch
//    events, exact fit for BT=262144). MARKER: occupancy >80% = confirmed.
//
// Identity (R7): full[j] = root @ X_j, root orthonormal =>
// local[j] = X_parent^T @ X_j; joints 1,2,3: local = X_j; joint 0: root.
//
// Lane tables (byte-packed u64s; lane l = tid&15):
//   joints: {0,1,2,3,4,5,6,9,12,13,14,15,16,17,18,19}
//   srcj:   sel<<4|row  (sel 0 = glb row, 1 = ori row)
//   pl:     parent's lane within the 16-group (lanes 0-3 unused: direct)
// Ignored joints {7,8,10,11,20,21,22,23} -> zeros, written by lanes 0-7.

__device__ __forceinline__ void rot6d_v(float2 u0, float2 u1, float2 u2, float M[3][3]) {
    float a1x = u0.x, a1y = u0.y, a1z = u1.x;
    float a2x = u1.y, a2y = u2.x, a2z = u2.y;
    float r1 = __builtin_amdgcn_rsqf(a1x * a1x + a1y * a1y + a1z * a1z);
    float b1x = a1x * r1, b1y = a1y * r1, b1z = a1z * r1;
    float dt = b1x * a2x + b1y * a2y + b1z * a2z;
    float c2x = a2x - dt * b1x, c2y = a2y - dt * b1y, c2z = a2z - dt * b1z;
    float r2 = __builtin_amdgcn_rsqf(c2x * c2x + c2y * c2y + c2z * c2z);
    float b2x = c2x * r2, b2y = c2y * r2, b2z = c2z * r2;
    float b3x = b1y * b2z - b1z * b2y;
    float b3y = b1z * b2x - b1x * b2z;
    float b3z = b1x * b2y - b1y * b2x;
    M[0][0] = b1x; M[0][1] = b1y; M[0][2] = b1z;
    M[1][0] = b2x; M[1][1] = b2y; M[1][2] = b2z;
    M[2][0] = b3x; M[2][1] = b3y; M[2][2] = b3z;
}

// C = A^T @ B
__device__ __forceinline__ void matTmul(const float A[3][3], const float B[3][3], float C[3][3]) {
#pragma unroll
    for (int i = 0; i < 3; ++i)
#pragma unroll
        for (int j = 0; j < 3; ++j)
            C[i][j] = A[0][i] * B[0][j] + A[1][i] * B[1][j] + A[2][i] * B[2][j];
}

// atan2(y,x) for y >= 0, result in [0, pi]. Minimax atan poly on [0,1], err ~2e-8.
__device__ __forceinline__ float atan2_pos(float y, float x) {
    float ax = fabsf(x);
    float mx = fmaxf(y, ax);
    float mn = fminf(y, ax);
    float a = mn * __builtin_amdgcn_rcpf(mx);
    float s = a * a;
    float p = -0.0040540580f;
    p = fmaf(p, s, 0.0218612288f);
    p = fmaf(p, s, -0.0559098861f);
    p = fmaf(p, s, 0.0964200441f);
    p = fmaf(p, s, -0.1390853351f);
    p = fmaf(p, s, 0.1994653599f);
    p = fmaf(p, s, -0.3332985605f);
    p = fmaf(p, s, 0.9999993329f);
    float r = p * a;
    r = (y > ax) ? (1.5707963268f - r) : r;
    r = (x < 0.f) ? (3.1415926536f - r) : r;
    return r;
}

__device__ __forceinline__ void mat2aa(const float m[3][3], float* __restrict__ outp) {
    float m00 = m[0][0], m01 = m[0][1], m02 = m[0][2];
    float m10 = m[1][0], m11 = m[1][1], m12 = m[1][2];
    float m20 = m[2][0], m21 = m[2][1], m22 = m[2][2];
    float t0 = fmaxf(1.f + m00 + m11 + m22, 0.f);
    float t1 = fmaxf(1.f + m00 - m11 - m22, 0.f);
    float t2 = fmaxf(1.f - m00 + m11 - m22, 0.f);
    float t3 = fmaxf(1.f - m00 - m11 + m22, 0.f);
    // argmax over t == argmax over sqrt(t) (monotonic, same first-max ties)
    int idx = 0;
    float bt = t0;
    if (t1 > bt) { bt = t1; idx = 1; }
    if (t2 > bt) { bt = t2; idx = 2; }
    if (t3 > bt) { bt = t3; idx = 3; }
    float best = __builtin_amdgcn_sqrtf(bt);  // >= 1 always (sum of t == 4)
    float s1 = m21 - m12, s2 = m02 - m20, s3 = m10 - m01;
    float p1 = m10 + m01, p2 = m02 + m20, p3 = m12 + m21;
    float w = (idx == 0) ? bt : (idx == 1) ? s1 : (idx == 2) ? s2 : s3;
    float x = (idx == 0) ? s1 : (idx == 1) ? bt : (idx == 2) ? p1 : p2;
    float y = (idx == 0) ? s2 : (idx == 1) ? p1 : (idx == 2) ? bt : p3;
    float z = (idx == 0) ? s3 : (idx == 1) ? p2 : (idx == 2) ? p3 : bt;
    float inv = 0.5f * __builtin_amdgcn_rcpf(fmaxf(best, 0.1f));
    w *= inv; x *= inv; y *= inv; z *= inv;
    // unit quaternion: sin(half) == |v|, cos(half) == w
    float n = __builtin_amdgcn_sqrtf(x * x + y * y + z * z);
    float half = atan2_pos(n, w);
    float angle = 2.f * half;
    // angle < 1e-6 => ref's (0.5 - angle^2/48) rounds to 0.5 => inv_sh = 2
    float inv_sh = (angle < 1e-6f) ? 2.f : angle * __builtin_amdgcn_rcpf(n);
    outp[0] = x * inv_sh;
    outp[1] = y * inv_sh;
    outp[2] = z * inv_sh;
}

__global__ __launch_bounds__(1024) void pose_kernel(const float* __restrict__ glb,
                                                    const float* __restrict__ ori,
                                                    float* __restrict__ out, int BT) {
    int tid = blockIdx.x * 1024 + threadIdx.x;
    unsigned e = (unsigned)tid >> 4;
    if (e >= (unsigned)BT) return;
    int l = tid & 15;

    // byte-packed per-lane tables
    const unsigned long long OUT3_LO = 0x1B120F0C09060300ULL;  // joint*3, lanes 0-7
    const unsigned long long OUT3_HI = 0x393633302D2A2724ULL;  // lanes 8-15
    const unsigned long long SRCJ_LO = 0x0403121102010010ULL;
    const unsigned long long SRCJ_HI = 0x1514090813070605ULL;
    const unsigned long long PL_LO   = 0x0603020100000000ULL;  // parent lane, lanes 4-7
    const unsigned long long PL_HI   = 0x0D0C0A0908070707ULL;  // lanes 8-15
    const unsigned long long IGN3    = 0x45423F3C211E1815ULL;  // ignored joint*3, lanes 0-7

    int sh = (l & 7) * 8;
    unsigned out3 = (unsigned)(((l < 8 ? OUT3_LO : OUT3_HI) >> sh) & 0xFF);
    unsigned srcj = (unsigned)(((l < 8 ? SRCJ_LO : SRCJ_HI) >> sh) & 0xFF);
    int pl = (int)(((l < 8 ? PL_LO : PL_HI) >> sh) & 0xFF);

    // 32-bit offsets (e <= 2^24, products < 2^32): sgpr-base + voffset loads
    unsigned row6 = (srcj & 15) * 6;
    unsigned goff = __umul24(e, 60u) + row6;
    unsigned ooff = __umul24(e, 36u) + row6;
    const float* src = (srcj & 0x10) ? (ori + ooff) : (glb + goff);
    const float2* s2 = (const float2*)src;   // rows are 24B -> 8B aligned
    float2 u0 = s2[0], u1 = s2[1], u2 = s2[2];

    float X[3][3];
    rot6d_v(u0, u1, u2, X);

    // parent's X from the parent's lane (wave-synchronous, 16-lane groups)
    float Xp[3][3];
    {
        const float* xf = &X[0][0];
        float* pf = &Xp[0][0];
#pragma unroll
        for (int k = 0; k < 9; ++k) pf[k] = __shfl(xf[k], pl, 16);
    }

    // local = Xp^T @ X; lanes 0-3: local = X (parent is root / joint 0 is root)
    float L[3][3];
    matTmul(Xp, X, L);
#pragma unroll
    for (int i = 0; i < 3; ++i)
#pragma unroll
        for (int j = 0; j < 3; ++j)
            L[i][j] = (l < 4) ? X[i][j] : L[i][j];

    float* oute = out + __umul24(e, 72u);
    mat2aa(L, oute + out3);

    // ignored joints -> exact zeros (lanes 0-7, one each)
    if (l < 8) {
        unsigned z = (unsigned)((IGN3 >> sh) & 0xFF);
        float* zp = oute + z;
        zp[0] = 0.f; zp[1] = 0.f; zp[2] = 0.f;
    }
}

extern "C" void kernel_launch(void* const* d_in, const int* in_sizes, int n_in,
                              void* d_out, int out_size, void* d_ws, size_t ws_size,
                              hipStream_t stream) {
    const float* glb = (const float*)d_in[0];   // (BT,10,6) f32
    const float* ori = (const float*)d_in[1];   // (BT,6,6)  f32
    float* out = (float*)d_out;                 // (BT,24,3) f32
    int BT = in_sizes[0] / 60;
    long long threads = (long long)BT * 16;
    int block = 1024;
    int grid = (int)((threads + block - 1) / block);
    pose_kernel<<<grid, block, 0, stream>>>(glb, ori, out, BT);
}